// Round 1
// baseline (3387.139 us; speedup 1.0000x reference)
//
#include <hip/hip_runtime.h>

#define NTAGS  256
#define TLEN   512
#define BATCH  256
#define PL     128          // prev rows resident in LDS (0..127); rest in VGPRs
#define STRIDE 132          // LDS column stride in floats (bank-balanced, 16B aligned)
#define NEGINF (-3.0e38f)

// One workgroup per batch. thread c owns output tag column c.
// LDS: transposed transitions rows 0..127 (transL[c*STRIDE+p] = trans[p][c]),
//      ping-pong alpha buffers. Registers: trans rows 128..255 column c.
__global__ __launch_bounds__(256, 1)
void viterbi_dp(const float* __restrict__ emis,   // [B][T][N]
                const float* __restrict__ mask,   // [B][T]
                const float* __restrict__ trans,  // [N][N]
                float* __restrict__ out,          // [B] scores ++ [B][T] paths (as float)
                unsigned char* __restrict__ bpt)  // [B][T-1][N] backpointers
{
    __shared__ __align__(16) float transL[NTAGS * STRIDE];
    __shared__ __align__(16) float alphaBuf[2][NTAGS];
    __shared__ __align__(16) float endScore[NTAGS];

    const int c = threadIdx.x;
    const int b = blockIdx.x;

    // Stage trans rows 0..PL-1 into LDS, transposed (coalesced global reads).
    for (int p = 0; p < PL; ++p)
        transL[c * STRIDE + p] = trans[p * NTAGS + c];

    // Rows PL..255 of column c live in registers.
    float treg[NTAGS - PL];
#pragma unroll
    for (int p = 0; p < NTAGS - PL; ++p)
        treg[p] = trans[(PL + p) * NTAGS + c];

    const float* eb = emis + (size_t)b * TLEN * NTAGS;
    const float* mb = mask + (size_t)b * TLEN;
    unsigned char* bb = bpt + (size_t)b * (TLEN - 1) * NTAGS;

    // alphas0 = trans[SOS=0][c] + em[b][0][c]
    float aOld = trans[c] + eb[c];
    alphaBuf[0][c] = aOld;
    __syncthreads();

    // software-pipeline emissions/mask one step ahead
    float emCur = eb[NTAGS + c];
    float mCur  = mb[1];

    int cur = 0;
    for (int t = 1; t < TLEN; ++t) {
        float emNext = 0.0f, mNext = 1.0f;
        if (t + 1 < TLEN) {
            emNext = eb[(t + 1) * NTAGS + c];
            mNext  = mb[t + 1];
        }
        const float* alpha = alphaBuf[cur];

        // scan prev ascending in 4 groups of 64; strict > keeps FIRST max
        // (matches jnp.argmax). Score = (alpha[p] + trans[p][c]) + em[c],
        // rounded exactly like the reference.
        float bg[4];
        int   ag[4];
#pragma unroll
        for (int g = 0; g < 4; ++g) {
            float gb = NEGINF;
            int   ga = 0;
#pragma unroll
            for (int q = 0; q < 16; ++q) {
                const int p0 = g * 64 + q * 4;
                const float4 al = *(const float4*)(alpha + p0);
                float4 tr;
                if (g < 2) {
                    tr = *(const float4*)(transL + c * STRIDE + p0);
                } else {
                    tr.x = treg[p0 - PL + 0];
                    tr.y = treg[p0 - PL + 1];
                    tr.z = treg[p0 - PL + 2];
                    tr.w = treg[p0 - PL + 3];
                }
                float s;
                s = (al.x + tr.x) + emCur; if (s > gb) { gb = s; ga = q * 4 + 0; }
                s = (al.y + tr.y) + emCur; if (s > gb) { gb = s; ga = q * 4 + 1; }
                s = (al.z + tr.z) + emCur; if (s > gb) { gb = s; ga = q * 4 + 2; }
                s = (al.w + tr.w) + emCur; if (s > gb) { gb = s; ga = q * 4 + 3; }
            }
            bg[g] = gb; ag[g] = ga;
        }
        float best = bg[0]; int arg = ag[0];
        if (bg[1] > best) { best = bg[1]; arg = 64  + ag[1]; }
        if (bg[2] > best) { best = bg[2]; arg = 128 + ag[2]; }
        if (bg[3] > best) { best = bg[3]; arg = 192 + ag[3]; }

        // masked blend exactly as reference: m*max + (1-m)*alpha
        float aNew = mCur * best + (1.0f - mCur) * aOld;
        bb[(size_t)(t - 1) * NTAGS + c] = (unsigned char)arg;
        alphaBuf[cur ^ 1][c] = aNew;
        aOld  = aNew;
        emCur = emNext;
        mCur  = mNext;
        cur ^= 1;
        __syncthreads();
    }

    // end_scores = alpha + trans[:, EOS=1]
    endScore[c] = aOld + trans[c * NTAGS + 1];
    __syncthreads();

    if (c == 0) {
        float best = endScore[0]; int arg = 0;
        for (int i = 1; i < NTAGS; ++i) {
            float v = endScore[i];
            if (v > best) { best = v; arg = i; }
        }
        out[b] = best;

        // backtrace (serial per batch; bpt region is L2-hot)
        float* pout = out + BATCH + (size_t)b * TLEN;
        int tag = arg;
        pout[TLEN - 1] = (float)tag;
        for (int t = TLEN - 2; t >= 0; --t) {
            tag = bb[(size_t)t * NTAGS + tag];
            pout[t] = (float)tag;
        }
    }
}

extern "C" void kernel_launch(void* const* d_in, const int* in_sizes, int n_in,
                              void* d_out, int out_size, void* d_ws, size_t ws_size,
                              hipStream_t stream) {
    const float* emis  = (const float*)d_in[0];
    const float* mask  = (const float*)d_in[1];
    const float* trans = (const float*)d_in[2];
    float* out = (float*)d_out;
    unsigned char* bpt = (unsigned char*)d_ws;  // needs 256*511*256 = 33.5 MB

    viterbi_dp<<<dim3(BATCH), dim3(NTAGS), 0, stream>>>(emis, mask, trans, out, bpt);
}

// Round 2
// 1168.378 us; speedup vs baseline: 2.8990x; 2.8990x over previous
//
#include <hip/hip_runtime.h>

#define NTAGS  256
#define TLEN   512
#define BATCH  256
#define HSPLIT 4
#define PP     64            // prev rows per thread
#define NEGINF (-3.0e38f)

// One workgroup (1024 threads) per batch. Thread (c, h): c = output tag
// column, h = prev-quarter. trans[64h+p][c] lives in 64 VGPRs per thread;
// alpha ping-pong + partials + backpointers live in LDS (no global bpt).
__global__ __launch_bounds__(1024, 4)
void viterbi_dp(const float* __restrict__ emis,   // [B][T][N]
                const float* __restrict__ mask,   // [B][T]
                const float* __restrict__ trans,  // [N][N]
                float* __restrict__ out)          // [B] scores ++ [B][T] paths (float)
{
    __shared__ __align__(16) float alphaBuf[2][NTAGS];
    __shared__ __align__(16) float pval[HSPLIT][NTAGS];
    __shared__ __align__(16) int   parg[HSPLIT][NTAGS];
    __shared__ unsigned char bptL[(TLEN - 1) * NTAGS];   // 130816 B
    __shared__ float endScore[NTAGS];

    const int tid = threadIdx.x;
    const int c = tid & (NTAGS - 1);
    const int h = tid >> 8;            // wave-uniform (waves of 64, h = tid/256)
    const int b = blockIdx.x;

    // My 64 transition values: trans[64h+p][c]. Coalesced (c consecutive per
    // lane), startup-only, then register-resident for the whole DP.
    float treg[PP];
#pragma unroll
    for (int p = 0; p < PP; ++p)
        treg[p] = trans[(h * PP + p) * NTAGS + c];

    const float* eb = emis + (size_t)b * TLEN * NTAGS;
    const float* mb = mask + (size_t)b * TLEN;

    // alphas0 = trans[SOS=0][c] + em[b][0][c]
    if (h == 0) alphaBuf[0][c] = trans[c] + eb[c];
    __syncthreads();

    // software-pipeline emissions/mask one step ahead
    float emCur = eb[NTAGS + c];
    float mCur  = mb[1];

    int cur = 0;
    for (int t = 1; t < TLEN; ++t) {
        float emNext = 0.0f, mNext = 1.0f;
        if (t + 1 < TLEN) {
            emNext = eb[(t + 1) * NTAGS + c];
            mNext  = mb[t + 1];
        }

        // partial max/argmax over my 64 prevs, ascending, strict > (first max),
        // rounding exactly as reference: (alpha[p] + trans[p][c]) + em[c]
        const float* alpha = alphaBuf[cur] + h * PP;   // wave-uniform address -> LDS broadcast
        float gb = NEGINF;
        int   ga = 0;
#pragma unroll
        for (int q = 0; q < PP / 4; ++q) {
            const float4 al = *(const float4*)(alpha + 4 * q);
            float s;
            s = (al.x + treg[4 * q + 0]) + emCur; if (s > gb) { gb = s; ga = 4 * q + 0; }
            s = (al.y + treg[4 * q + 1]) + emCur; if (s > gb) { gb = s; ga = 4 * q + 1; }
            s = (al.z + treg[4 * q + 2]) + emCur; if (s > gb) { gb = s; ga = 4 * q + 2; }
            s = (al.w + treg[4 * q + 3]) + emCur; if (s > gb) { gb = s; ga = 4 * q + 3; }
        }
        pval[h][c] = gb;
        parg[h][c] = ga;
        __syncthreads();

        // combine across h (waves 0-3 only; wave-uniform branch), h ascending
        // with strict > keeps the global FIRST argmax.
        if (h == 0) {
            float best = pval[0][c]; int arg = parg[0][c];
            float v1 = pval[1][c], v2 = pval[2][c], v3 = pval[3][c];
            if (v1 > best) { best = v1; arg =  64 + parg[1][c]; }
            if (v2 > best) { best = v2; arg = 128 + parg[2][c]; }
            if (v3 > best) { best = v3; arg = 192 + parg[3][c]; }
            const float aOld = alphaBuf[cur][c];
            alphaBuf[cur ^ 1][c] = mCur * best + (1.0f - mCur) * aOld;
            bptL[(t - 1) * NTAGS + c] = (unsigned char)arg;
        }
        emCur = emNext;
        mCur  = mNext;
        cur ^= 1;
        __syncthreads();
    }

    // end_scores = alpha + trans[:, EOS=1]
    if (h == 0) endScore[c] = alphaBuf[cur][c] + trans[c * NTAGS + 1];
    __syncthreads();

    if (tid == 0) {
        float best = endScore[0]; int arg = 0;
        for (int i = 1; i < NTAGS; ++i) {
            float v = endScore[i];
            if (v > best) { best = v; arg = i; }
        }
        out[b] = best;

        // backtrace entirely from LDS
        float* pout = out + BATCH + (size_t)b * TLEN;
        int tag = arg;
        pout[TLEN - 1] = (float)tag;
        for (int t = TLEN - 2; t >= 0; --t) {
            tag = bptL[t * NTAGS + tag];
            pout[t] = (float)tag;
        }
    }
}

extern "C" void kernel_launch(void* const* d_in, const int* in_sizes, int n_in,
                              void* d_out, int out_size, void* d_ws, size_t ws_size,
                              hipStream_t stream) {
    (void)d_ws; (void)ws_size; (void)in_sizes; (void)n_in; (void)out_size;
    const float* emis  = (const float*)d_in[0];
    const float* mask  = (const float*)d_in[1];
    const float* trans = (const float*)d_in[2];
    float* out = (float*)d_out;

    viterbi_dp<<<dim3(BATCH), dim3(1024), 0, stream>>>(emis, mask, trans, out);
}

// Round 3
// 1123.672 us; speedup vs baseline: 3.0143x; 1.0398x over previous
//
#include <hip/hip_runtime.h>

#define NTAGS  256
#define TLEN   512
#define BATCH  256
#define NEGINF (-3.0e38f)

// One workgroup (1024 threads) per batch. Thread (c, h): c = output tag
// column (tid & 255), h = prev-quarter (tid >> 8). trans[64h+p][c] is held in
// 64 NAMED float registers (asm-pinned so the compiler can't rematerialize
// the loads inside the t-loop — round-2 showed it reloads from L2 otherwise).
// Alpha (single buffer), partials, and backpointers live in LDS.
__global__ __launch_bounds__(1024, 4)
void viterbi_dp(const float* __restrict__ emis,   // [B][T][N]
                const float* __restrict__ mask,   // [B][T]
                const float* __restrict__ trans,  // [N][N]
                float* __restrict__ out)          // [B] scores ++ [B][T] paths (float)
{
    __shared__ __align__(16) float  alphaBuf[NTAGS];
    __shared__ __align__(16) float2 pv[3][NTAGS];          // partials of h=1..3
    __shared__ unsigned char bptL[(TLEN - 1) * NTAGS];     // 130816 B
    __shared__ float endScore[NTAGS];

    const int tid = threadIdx.x;
    const int c = tid & (NTAGS - 1);
    const int h = tid >> 8;            // wave-uniform
    const int b = blockIdx.x;
    const int pbase = h * 64;

    // ---- 64 named transition registers: t<i> = trans[pbase + i][c] ----
#define LDT(i) float t##i = trans[(pbase + (i)) * NTAGS + c];
    LDT(0)  LDT(1)  LDT(2)  LDT(3)  LDT(4)  LDT(5)  LDT(6)  LDT(7)
    LDT(8)  LDT(9)  LDT(10) LDT(11) LDT(12) LDT(13) LDT(14) LDT(15)
    LDT(16) LDT(17) LDT(18) LDT(19) LDT(20) LDT(21) LDT(22) LDT(23)
    LDT(24) LDT(25) LDT(26) LDT(27) LDT(28) LDT(29) LDT(30) LDT(31)
    LDT(32) LDT(33) LDT(34) LDT(35) LDT(36) LDT(37) LDT(38) LDT(39)
    LDT(40) LDT(41) LDT(42) LDT(43) LDT(44) LDT(45) LDT(46) LDT(47)
    LDT(48) LDT(49) LDT(50) LDT(51) LDT(52) LDT(53) LDT(54) LDT(55)
    LDT(56) LDT(57) LDT(58) LDT(59) LDT(60) LDT(61) LDT(62) LDT(63)
#undef LDT
    // Pin: makes each value the result of an opaque op — no remat possible.
#define PIN8(a,b_,c_,d_,e_,f_,g_,h_) \
    asm volatile("" : "+v"(a),"+v"(b_),"+v"(c_),"+v"(d_),"+v"(e_),"+v"(f_),"+v"(g_),"+v"(h_));
    PIN8(t0,t1,t2,t3,t4,t5,t6,t7)
    PIN8(t8,t9,t10,t11,t12,t13,t14,t15)
    PIN8(t16,t17,t18,t19,t20,t21,t22,t23)
    PIN8(t24,t25,t26,t27,t28,t29,t30,t31)
    PIN8(t32,t33,t34,t35,t36,t37,t38,t39)
    PIN8(t40,t41,t42,t43,t44,t45,t46,t47)
    PIN8(t48,t49,t50,t51,t52,t53,t54,t55)
    PIN8(t56,t57,t58,t59,t60,t61,t62,t63)
#undef PIN8

    const float* eb = emis + (size_t)b * TLEN * NTAGS;
    const float* mb = mask + (size_t)b * TLEN;

    // alphas0 = trans[SOS=0][c] + em[b][0][c]
    if (h == 0) alphaBuf[c] = trans[c] + eb[c];
    __syncthreads();

    // software-pipeline emissions/mask one step ahead
    float emCur = eb[NTAGS + c];
    float mCur  = mb[1];

    const float4* alpha4 = (const float4*)(alphaBuf + pbase);  // wave-uniform -> broadcast

    for (int t = 1; t < TLEN; ++t) {
        float emNext = 0.0f, mNext = 1.0f;
        if (t + 1 < TLEN) {
            emNext = eb[(t + 1) * NTAGS + c];
            mNext  = mb[t + 1];
        }

        // partial max/argmax over my 64 prevs, ascending, strict > (first max),
        // rounding exactly as reference: (alpha[p] + trans[p][c]) + em[c]
        float gb = NEGINF;
        int   ga = 0;
#define QSTEP(q, A, B, C, D) { \
        const float4 al = alpha4[q]; float s; \
        s = (al.x + A) + emCur; if (s > gb) { gb = s; ga = 4*(q) + 0; } \
        s = (al.y + B) + emCur; if (s > gb) { gb = s; ga = 4*(q) + 1; } \
        s = (al.z + C) + emCur; if (s > gb) { gb = s; ga = 4*(q) + 2; } \
        s = (al.w + D) + emCur; if (s > gb) { gb = s; ga = 4*(q) + 3; } }
        QSTEP(0,  t0,  t1,  t2,  t3)
        QSTEP(1,  t4,  t5,  t6,  t7)
        QSTEP(2,  t8,  t9,  t10, t11)
        QSTEP(3,  t12, t13, t14, t15)
        QSTEP(4,  t16, t17, t18, t19)
        QSTEP(5,  t20, t21, t22, t23)
        QSTEP(6,  t24, t25, t26, t27)
        QSTEP(7,  t28, t29, t30, t31)
        QSTEP(8,  t32, t33, t34, t35)
        QSTEP(9,  t36, t37, t38, t39)
        QSTEP(10, t40, t41, t42, t43)
        QSTEP(11, t44, t45, t46, t47)
        QSTEP(12, t48, t49, t50, t51)
        QSTEP(13, t52, t53, t54, t55)
        QSTEP(14, t56, t57, t58, t59)
        QSTEP(15, t60, t61, t62, t63)
#undef QSTEP

        if (h) pv[h - 1][c] = make_float2(gb, __int_as_float(ga + pbase));
        __syncthreads();

        // combine across h (h==0 waves only), h ascending, strict > keeps
        // the global FIRST argmax.
        if (h == 0) {
            const float2 P1 = pv[0][c];
            const float2 P2 = pv[1][c];
            const float2 P3 = pv[2][c];
            float best = gb; int arg = ga;
            if (P1.x > best) { best = P1.x; arg = __float_as_int(P1.y); }
            if (P2.x > best) { best = P2.x; arg = __float_as_int(P2.y); }
            if (P3.x > best) { best = P3.x; arg = __float_as_int(P3.y); }
            const float aOld = alphaBuf[c];
            alphaBuf[c] = mCur * best + (1.0f - mCur) * aOld;
            bptL[(t - 1) * NTAGS + c] = (unsigned char)arg;
        }
        emCur = emNext;
        mCur  = mNext;
        __syncthreads();
    }

    // end_scores = alpha + trans[:, EOS=1]
    if (h == 0) endScore[c] = alphaBuf[c] + trans[c * NTAGS + 1];
    __syncthreads();

    if (tid == 0) {
        float best = endScore[0]; int arg = 0;
        for (int i = 1; i < NTAGS; ++i) {
            float v = endScore[i];
            if (v > best) { best = v; arg = i; }
        }
        out[b] = best;

        // backtrace entirely from LDS
        float* pout = out + BATCH + (size_t)b * TLEN;
        int tag = arg;
        pout[TLEN - 1] = (float)tag;
        for (int t = TLEN - 2; t >= 0; --t) {
            tag = bptL[t * NTAGS + tag];
            pout[t] = (float)tag;
        }
    }
}

extern "C" void kernel_launch(void* const* d_in, const int* in_sizes, int n_in,
                              void* d_out, int out_size, void* d_ws, size_t ws_size,
                              hipStream_t stream) {
    (void)d_ws; (void)ws_size; (void)in_sizes; (void)n_in; (void)out_size;
    const float* emis  = (const float*)d_in[0];
    const float* mask  = (const float*)d_in[1];
    const float* trans = (const float*)d_in[2];
    float* out = (float*)d_out;

    viterbi_dp<<<dim3(BATCH), dim3(1024), 0, stream>>>(emis, mask, trans, out);
}